// Round 1
// 433.875 us; speedup vs baseline: 1.0735x; 1.0735x over previous
//
#include <hip/hip_runtime.h>
#include <hip/hip_bf16.h>

#define N_NODES 38332
#define POI_LEN 38333
#define CAT_LEN 400
#define POI_DIM 300
#define CAT_DIM 100
#define N_EDGES (N_NODES * 32)
#define NEG_SLOPE 0.01f
#define B1 ((N_NODES + 127) / 128)        // 300 dst-buckets (128 dsts each)
#define SPLIT_CHUNK 4096
#define NSPLIT ((N_EDGES + SPLIT_CHUNK - 1) / SPLIT_CHUNK)  // 300
#define PLACE_CAP 8192
#define BCAP 8192                          // per-bucket staging/csr capacity

typedef __attribute__((ext_vector_type(8))) short short8;
typedef __attribute__((ext_vector_type(4))) float f32x4;

__device__ __forceinline__ unsigned short f2bf(float f) {
  unsigned u = __float_as_uint(f);
  u += 0x7fff + ((u >> 16) & 1);  // RNE
  return (unsigned short)(u >> 16);
}
__device__ __forceinline__ float bflo(unsigned u) {
  return __uint_as_float(u << 16);
}
__device__ __forceinline__ float bfhi(unsigned u) {
  return __uint_as_float(u & 0xffff0000u);
}

// ---------------- prep: zero counters + all W swizzles in ONE kernel -------
// wf layout (B-frag order): idx = (((ks*4+q)*64 + n)*8 + j), k = ks*32+q*8+j

#define WFIN_ELEMS (13 * 2048)   // K_pad=416 -> 26624
#define WFGCN_ELEMS (5 * 4096)

__global__ __launch_bounds__(256) void k_prep(const float* __restrict__ W_in,
                                              const float* __restrict__ gcn_Ws,
                                              unsigned short* __restrict__ wf_in,
                                              unsigned short* __restrict__ wf_gcn,
                                              int* __restrict__ bcnt,
                                              float* __restrict__ h128) {
  int idx = blockIdx.x * 256 + threadIdx.x;
  if (idx < B1) bcnt[idx] = 0;
  if (idx < 128) h128[idx] = 0.f;
  if (idx < WFIN_ELEMS) {
    int j = idx & 7, n = (idx >> 3) & 63, q = (idx >> 9) & 3, ks = idx >> 11;
    int k = ks * 32 + q * 8 + j;
    wf_in[idx] = f2bf((k < 400) ? W_in[k * 64 + n] : 0.f);
  } else if (idx < WFIN_ELEMS + WFGCN_ELEMS) {
    int t = idx - WFIN_ELEMS;
    int l = t >> 12, i = t & 4095;
    int j = i & 7, n = (i >> 3) & 63, q = (i >> 9) & 3, ks = i >> 11;
    int k = ks * 32 + q * 8 + j;
    wf_gcn[t] = f2bf(gcn_Ws[(size_t)l * 4096 + k * 64 + n]);
  }
}

// ---------------- CSR build (count-free, two-level, packed staging) --------
// staging entry packs (src << 7) | (dst & 127): src < 38332 < 2^16 fits.

__global__ __launch_bounds__(256) void k_split(const int* __restrict__ src,
                                               const int* __restrict__ dst,
                                               int* __restrict__ bcnt,
                                               int* __restrict__ staging) {
  __shared__ int hist[B1];
  __shared__ int lbase[B1];
  __shared__ int lcur[B1];
  int tid = threadIdx.x;
  int base = blockIdx.x * SPLIT_CHUNK;
  int n = N_EDGES - base;
  if (n > SPLIT_CHUNK) n = SPLIT_CHUNK;
  for (int b = tid; b < B1; b += 256) {
    hist[b] = 0;
    lcur[b] = 0;
  }
  __syncthreads();
  for (int i = tid; i < n; i += 256) atomicAdd(&hist[dst[base + i] >> 7], 1);
  __syncthreads();
  for (int b = tid; b < B1; b += 256) {
    int c = hist[b];
    lbase[b] = c ? atomicAdd(&bcnt[b], c) : 0;
  }
  __syncthreads();
  for (int i = tid; i < n; i += 256) {
    int d = dst[base + i];
    int s = src[base + i];
    int b = d >> 7;
    int off = atomicAdd(&lcur[b], 1);
    staging[(size_t)b * BCAP + lbase[b] + off] = (s << 7) | (d & 127);
  }
}

// per bucket: local histogram + scan -> rs(start,cnt)/dinv, exact placement
// in LDS, coalesced copy-out into the bucket's fixed csr region (no global
// prefix scan needed -> k_bscan eliminated).
__global__ __launch_bounds__(256) void k_place(const int* __restrict__ staging,
                                               const int* __restrict__ bcnt,
                                               int* __restrict__ csr_src,
                                               int2* __restrict__ rs,
                                               float* __restrict__ dinv) {
  __shared__ int lc[128];
  __shared__ int ls[256];
  __shared__ int cur[128];
  __shared__ int buf[PLACE_CAP];
  int b = blockIdx.x;
  int tid = threadIdx.x;
  int d0 = b * 128;
  int nd = N_NODES - d0;
  if (nd > 128) nd = 128;
  int cnt_b = bcnt[b];
  const int* st = staging + (size_t)b * BCAP;
  if (tid < 128) lc[tid] = 0;
  __syncthreads();
  for (int i = tid; i < cnt_b; i += 256) atomicAdd(&lc[st[i] & 127], 1);
  __syncthreads();
  int v = (tid < 128) ? lc[tid] : 0;
  ls[tid] = v;
  __syncthreads();
  for (int off = 1; off < 128; off <<= 1) {
    int t = (tid >= off) ? ls[tid - off] : 0;
    __syncthreads();
    ls[tid] += t;
    __syncthreads();
  }
  if (tid < 128) {
    int excl = ls[tid] - v;
    cur[tid] = excl;
    if (tid < nd) {
      rs[d0 + tid] = make_int2(b * BCAP + excl, v);
      dinv[d0 + tid] = 1.0f / sqrtf((float)(v + 1));  // deg incl self loop
    }
  }
  __syncthreads();
  for (int i = tid; i < cnt_b; i += 256) {
    int p = st[i];
    int pos = atomicAdd(&cur[p & 127], 1);
    buf[pos] = p >> 7;
  }
  __syncthreads();
  int base = b * BCAP;
  for (int i = tid; i < cnt_b; i += 256) csr_src[base + i] = buf[i];
}

// ---------------- fused front-end: gather poi/cat rows + MFMA GEMM -> hs ---
// per block: 16 nodes. A-row = [poi_emb[pid] | cat_emb[cid]] (K=400, pad 416)
// epilogue adds x2..x4 * W_in[400..402] in f32 (numerics == baseline), then
// * dinv -> bf16 hs. Replaces projm_poi (full 46MB table), projm_cat, gather.

__global__ __launch_bounds__(256) void k_front(
    const float* __restrict__ x, const float* __restrict__ poi_emb,
    const float* __restrict__ cat_emb, const float* __restrict__ W_in,
    const unsigned short* __restrict__ wf_in, const float* __restrict__ dinv,
    unsigned short* __restrict__ hs) {
  constexpr int KP = 416, RS = 424, NK4 = 104;
  __shared__ unsigned short sA[16 * RS];
  __shared__ float sC[16 * 68];
  __shared__ int sPid[16], sCid[16];
  __shared__ float sX[16][3];
  int tid = threadIdx.x;
  int row0 = blockIdx.x * 16;
  if (tid < 16) {
    int row = row0 + tid;
    if (row < N_NODES) {
      sPid[tid] = (int)x[row * 5 + 0];
      sCid[tid] = (int)x[row * 5 + 1];
      sX[tid][0] = x[row * 5 + 2];
      sX[tid][1] = x[row * 5 + 3];
      sX[tid][2] = x[row * 5 + 4];
    } else {
      sPid[tid] = 0; sCid[tid] = 0;
      sX[tid][0] = sX[tid][1] = sX[tid][2] = 0.f;
    }
  }
  __syncthreads();
  for (int idx = tid; idx < 16 * NK4; idx += 256) {
    int r = idx / NK4;
    int k = (idx - r * NK4) * 4;
    ushort4 o = {0, 0, 0, 0};
    if (k < 400 && row0 + r < N_NODES) {
      float4 f;
      if (k < 300) f = *(const float4*)(poi_emb + (size_t)sPid[r] * 300 + k);
      else         f = *(const float4*)(cat_emb + (size_t)sCid[r] * 100 + (k - 300));
      o.x = f2bf(f.x); o.y = f2bf(f.y); o.z = f2bf(f.z); o.w = f2bf(f.w);
    }
    *(ushort4*)&sA[r * RS + k] = o;
  }
  __syncthreads();
  int lane = tid & 63, wv = tid >> 6;
  int c = lane & 15, q = lane >> 4, n0 = wv * 16;
  f32x4 acc = {0.f, 0.f, 0.f, 0.f};
  const unsigned short* arow = &sA[c * RS];
#pragma unroll
  for (int ks = 0; ks < KP / 32; ks++) {
    short8 af = *(const short8*)(arow + ks * 32 + q * 8);
    short8 bf = *(const short8*)(wf_in + ((size_t)((ks * 4 + q) * 64 + n0 + c)) * 8);
    acc = __builtin_amdgcn_mfma_f32_16x16x32_bf16(af, bf, acc, 0, 0, 0);
  }
#pragma unroll
  for (int r = 0; r < 4; r++) sC[(q * 4 + r) * 68 + n0 + c] = acc[r];
  __syncthreads();
  for (int idx = tid; idx < 16 * 64; idx += 256) {
    int r = idx >> 6, col = idx & 63;
    int row = row0 + r;
    if (row < N_NODES) {
      float v = sC[r * 68 + col] + sX[r][0] * W_in[400 * 64 + col] +
                sX[r][1] * W_in[401 * 64 + col] + sX[r][2] * W_in[402 * 64 + col];
      hs[(size_t)row * 64 + col] = f2bf(v * dinv[row]);
    }
  }
}

// ---------------- layer GEMM: hs = bf16((feat @ W) * dinv), feat is bf16 ---

__global__ __launch_bounds__(256) void k_projg(const unsigned short* __restrict__ A,
                                               const unsigned short* __restrict__ Wf,
                                               unsigned short* __restrict__ hs,
                                               const float* __restrict__ dinv) {
  constexpr int RS = 72;
  __shared__ unsigned short sA[16 * RS];
  __shared__ float sC[16 * 68];
  int tid = threadIdx.x;
  int row0 = blockIdx.x * 16;
  {
    int r = tid >> 4, k4 = (tid & 15) * 4;
    int row = row0 + r;
    ushort4 o = {0, 0, 0, 0};
    if (row < N_NODES) o = *(const ushort4*)(A + (size_t)row * 64 + k4);
    *(ushort4*)&sA[r * RS + k4] = o;
  }
  __syncthreads();
  int lane = tid & 63, wv = tid >> 6;
  int c = lane & 15, q = lane >> 4, n0 = wv * 16;
  f32x4 acc = {0.f, 0.f, 0.f, 0.f};
  const unsigned short* arow = &sA[c * RS];
#pragma unroll
  for (int ks = 0; ks < 2; ks++) {
    short8 af = *(const short8*)(arow + ks * 32 + q * 8);
    short8 bf = *(const short8*)(Wf + ((size_t)((ks * 4 + q) * 64 + n0 + c)) * 8);
    acc = __builtin_amdgcn_mfma_f32_16x16x32_bf16(af, bf, acc, 0, 0, 0);
  }
#pragma unroll
  for (int r = 0; r < 4; r++) sC[(q * 4 + r) * 68 + n0 + c] = acc[r];
  __syncthreads();
  for (int idx = tid; idx < 16 * 64; idx += 256) {
    int r = idx >> 6, col = idx & 63;
    int row = row0 + r;
    if (row < N_NODES) hs[(size_t)row * 64 + col] = f2bf(sC[r * 68 + col] * dinv[row]);
  }
}

// ---------------- aggregation: 4 gathers in flight, single accumulator ----
// wave = 1 dst node. lane = eslot(8) x ch8(8). 32 edges per loop iteration.
// MODE 0: feat = bf16(leaky(t))           (first layer)
// MODE 1: feat = bf16(leaky(t) + t)       (hidden layers)
// MODE 2: hs1 = (leaky(t)+t) . W_out * dinv   (last layer fused w/ out_xform;
//         no feat write)

template <int MODE>
__global__ __launch_bounds__(256) void k_agg(const unsigned short* __restrict__ hs,
                                             const int2* __restrict__ rs,
                                             const int* __restrict__ csr_src,
                                             const float* __restrict__ dinv,
                                             const float* __restrict__ bias,
                                             unsigned short* __restrict__ feat,
                                             const float* __restrict__ W_out,
                                             float* __restrict__ hs1) {
  int tid = threadIdx.x;
  int lane = tid & 63;
  int wv = tid >> 6;
  int node = blockIdx.x * 4 + wv;
  int eslot = lane >> 3;  // 0..7
  int ch8 = lane & 7;     // 8-channel group (16B) within 64-ch row
  int2 rr = rs[node];
  int r0 = rr.x, r1 = rr.x + rr.y;
  float4 a0 = {0.f, 0.f, 0.f, 0.f}, a1 = a0;
#define ACC8(v)                                                              \
  do {                                                                       \
    a0.x += bflo((v).x); a0.y += bfhi((v).x);                                \
    a0.z += bflo((v).y); a0.w += bfhi((v).y);                                \
    a1.x += bflo((v).z); a1.y += bfhi((v).z);                                \
    a1.z += bflo((v).w); a1.w += bfhi((v).w);                                \
  } while (0)
  int e = r0 + eslot;
  for (; e + 24 < r1; e += 32) {
    int s0 = csr_src[e];
    int s1 = csr_src[e + 8];
    int s2 = csr_src[e + 16];
    int s3 = csr_src[e + 24];
    uint4 v0 = *(const uint4*)(hs + (size_t)s0 * 64 + ch8 * 8);
    uint4 v1 = *(const uint4*)(hs + (size_t)s1 * 64 + ch8 * 8);
    uint4 v2 = *(const uint4*)(hs + (size_t)s2 * 64 + ch8 * 8);
    uint4 v3 = *(const uint4*)(hs + (size_t)s3 * 64 + ch8 * 8);
    ACC8(v0); ACC8(v1); ACC8(v2); ACC8(v3);
  }
  if (e + 8 < r1) {
    int s0 = csr_src[e];
    int s1 = csr_src[e + 8];
    uint4 v0 = *(const uint4*)(hs + (size_t)s0 * 64 + ch8 * 8);
    uint4 v1 = *(const uint4*)(hs + (size_t)s1 * 64 + ch8 * 8);
    ACC8(v0); ACC8(v1);
    e += 16;
  }
  if (e < r1) {
    int s = csr_src[e];
    uint4 v = *(const uint4*)(hs + (size_t)s * 64 + ch8 * 8);
    ACC8(v);
  }
#undef ACC8
#pragma unroll
  for (int off = 8; off <= 32; off <<= 1) {
    a0.x += __shfl_xor(a0.x, off, 64);
    a0.y += __shfl_xor(a0.y, off, 64);
    a0.z += __shfl_xor(a0.z, off, 64);
    a0.w += __shfl_xor(a0.w, off, 64);
    a1.x += __shfl_xor(a1.x, off, 64);
    a1.y += __shfl_xor(a1.y, off, 64);
    a1.z += __shfl_xor(a1.z, off, 64);
    a1.w += __shfl_xor(a1.w, off, 64);
  }
  if (lane < 8) {
    uint4 sv = *(const uint4*)(hs + (size_t)node * 64 + ch8 * 8);
    float4 bb0 = *(const float4*)(bias + ch8 * 8);
    float4 bb1 = *(const float4*)(bias + ch8 * 8 + 4);
    float dn = dinv[node];
    float4 t0, t1;
    t0.x = dn * (a0.x + bflo(sv.x)) + bb0.x;
    t0.y = dn * (a0.y + bfhi(sv.x)) + bb0.y;
    t0.z = dn * (a0.z + bflo(sv.y)) + bb0.z;
    t0.w = dn * (a0.w + bfhi(sv.y)) + bb0.w;
    t1.x = dn * (a1.x + bflo(sv.z)) + bb1.x;
    t1.y = dn * (a1.y + bfhi(sv.z)) + bb1.y;
    t1.z = dn * (a1.z + bflo(sv.w)) + bb1.z;
    t1.w = dn * (a1.w + bfhi(sv.w)) + bb1.w;
    float4 l0, l1, o0, o1;
    l0.x = (t0.x >= 0.f) ? t0.x : NEG_SLOPE * t0.x;
    l0.y = (t0.y >= 0.f) ? t0.y : NEG_SLOPE * t0.y;
    l0.z = (t0.z >= 0.f) ? t0.z : NEG_SLOPE * t0.z;
    l0.w = (t0.w >= 0.f) ? t0.w : NEG_SLOPE * t0.w;
    l1.x = (t1.x >= 0.f) ? t1.x : NEG_SLOPE * t1.x;
    l1.y = (t1.y >= 0.f) ? t1.y : NEG_SLOPE * t1.y;
    l1.z = (t1.z >= 0.f) ? t1.z : NEG_SLOPE * t1.z;
    l1.w = (t1.w >= 0.f) ? t1.w : NEG_SLOPE * t1.w;
    if (MODE == 0) {
      o0 = l0; o1 = l1;
    } else {
      o0.x = l0.x + t0.x; o0.y = l0.y + t0.y; o0.z = l0.z + t0.z; o0.w = l0.w + t0.w;
      o1.x = l1.x + t1.x; o1.y = l1.y + t1.y; o1.z = l1.z + t1.z; o1.w = l1.w + t1.w;
    }
    if (MODE == 2) {
      float4 w0 = *(const float4*)(W_out + ch8 * 8);
      float4 w1 = *(const float4*)(W_out + ch8 * 8 + 4);
      float p = o0.x * w0.x + o0.y * w0.y + o0.z * w0.z + o0.w * w0.w +
                o1.x * w1.x + o1.y * w1.y + o1.z * w1.z + o1.w * w1.w;
      p += __shfl_xor(p, 1, 64);
      p += __shfl_xor(p, 2, 64);
      p += __shfl_xor(p, 4, 64);
      if (lane == 0) hs1[node] = p * dn;
    } else {
      uint4 pk;
      pk.x = (unsigned)f2bf(o0.x) | ((unsigned)f2bf(o0.y) << 16);
      pk.y = (unsigned)f2bf(o0.z) | ((unsigned)f2bf(o0.w) << 16);
      pk.z = (unsigned)f2bf(o1.x) | ((unsigned)f2bf(o1.y) << 16);
      pk.w = (unsigned)f2bf(o1.z) | ((unsigned)f2bf(o1.w) << 16);
      *(uint4*)(feat + (size_t)node * 64 + ch8 * 8) = pk;
    }
  }
}

// ---------------- output aggregation (64 -> 1 head, post-xform) ------------

__global__ __launch_bounds__(256) void k_out_agg(const float* __restrict__ hs1,
                                                 const int2* __restrict__ rs,
                                                 const int* __restrict__ csr_src,
                                                 const float* __restrict__ dinv,
                                                 const float* __restrict__ b_out,
                                                 float* __restrict__ g) {
  int lane = threadIdx.x & 63;
  int w = threadIdx.x >> 6;
  int node = blockIdx.x * 4 + w;
  int2 rr = rs[node];
  int r0 = rr.x, r1 = rr.x + rr.y;
  float acc = 0.f;
  for (int e = r0 + lane; e < r1; e += 64) acc += hs1[csr_src[e]];
#pragma unroll
  for (int off = 32; off; off >>= 1) acc += __shfl_xor(acc, off, 64);
  if (lane == 0) {
    float t = dinv[node] * (acc + hs1[node]) + b_out[0];
    g[node] = (t >= 0.f) ? t : NEG_SLOPE * t;
  }
}

// ---------------- FC head ----------------

__global__ __launch_bounds__(128) void k_fc1(const float* __restrict__ g,
                                             const float* __restrict__ fc1_W,
                                             float* __restrict__ h128) {
  int j = threadIdx.x;  // 0..127
  int base = blockIdx.x * 32;
  int end = base + 32;
  if (end > N_NODES) end = N_NODES;
  float acc = 0.f;
  int i = base;
  for (; i + 4 <= end; i += 4) {
    acc += g[i + 0] * fc1_W[(size_t)(i + 0) * 128 + j];
    acc += g[i + 1] * fc1_W[(size_t)(i + 1) * 128 + j];
    acc += g[i + 2] * fc1_W[(size_t)(i + 2) * 128 + j];
    acc += g[i + 3] * fc1_W[(size_t)(i + 3) * 128 + j];
  }
  for (; i < end; i++) acc += g[i] * fc1_W[(size_t)i * 128 + j];
  atomicAdd(&h128[j], acc);
}

__global__ __launch_bounds__(256) void k_fc2(const float* __restrict__ h128raw,
                                             const float* __restrict__ fc1_b,
                                             const float* __restrict__ fc2_W,
                                             const float* __restrict__ fc2_b,
                                             float* __restrict__ out) {
  __shared__ float sh[128];
  int tid = threadIdx.x;
  if (tid < 128) {
    float v = h128raw[tid] + fc1_b[tid];
    sh[tid] = (v > 0.f) ? v : 0.f;
  }
  __syncthreads();
  int p = blockIdx.x * 256 + tid;
  if (p < POI_LEN) {
    float acc = fc2_b[p];
#pragma unroll 8
    for (int j = 0; j < 128; j++) acc += sh[j] * fc2_W[(size_t)j * POI_LEN + p];
    out[p] = (acc > 0.f) ? acc : 0.f;
  }
}

// ---------------- launch ----------------

extern "C" void kernel_launch(void* const* d_in, const int* in_sizes, int n_in,
                              void* d_out, int out_size, void* d_ws, size_t ws_size,
                              hipStream_t stream) {
  const float* x       = (const float*)d_in[0];
  const int*   ei      = (const int*)d_in[1];
  const float* poi_emb = (const float*)d_in[2];
  const float* cat_emb = (const float*)d_in[3];
  const float* W_in    = (const float*)d_in[4];
  const float* b_in    = (const float*)d_in[5];
  const float* gcn_Ws  = (const float*)d_in[6];
  const float* gcn_bs  = (const float*)d_in[7];
  const float* W_out   = (const float*)d_in[8];
  const float* b_out   = (const float*)d_in[9];
  const float* fc1_W   = (const float*)d_in[10];
  const float* fc1_b   = (const float*)d_in[11];
  const float* fc2_W   = (const float*)d_in[12];
  const float* fc2_b   = (const float*)d_in[13];
  const int* src = ei;
  const int* dst = ei + N_EDGES;

  char* p = (char*)d_ws;
  auto take = [&](size_t bytes) {
    char* r = p;
    p += (bytes + 255) & ~(size_t)255;
    return r;
  };
  int2*  rs        = (int2*)take((size_t)N_NODES * 8);
  float* dinv      = (float*)take((size_t)N_NODES * 4);
  int*   bcnt      = (int*)take((size_t)B1 * 4);
  int*   csr_src   = (int*)take((size_t)B1 * BCAP * 4);
  unsigned short* feat = (unsigned short*)take((size_t)N_NODES * 64 * 2);
  unsigned short* hs   = (unsigned short*)take((size_t)N_NODES * 64 * 2);
  float* hs1       = (float*)take((size_t)N_NODES * 4);
  float* g         = (float*)take((size_t)N_NODES * 4);
  float* h128      = (float*)take(128 * 4);
  unsigned short* wf_in  = (unsigned short*)take((size_t)WFIN_ELEMS * 2);
  unsigned short* wf_gcn = (unsigned short*)take((size_t)WFGCN_ELEMS * 2);
  // staging (9.83 MB int) aliases feat+hs+hs1 (9.97 MB) — all dead until
  // after k_place finishes reading staging.
  int* staging = (int*)feat;
  float* out = (float*)d_out;

  const int nb4 = N_NODES / 4;           // 9583
  const int nb16 = (N_NODES + 15) / 16;  // 2396

  k_prep<<<(WFIN_ELEMS + WFGCN_ELEMS + 255) / 256, 256, 0, stream>>>(
      W_in, gcn_Ws, wf_in, wf_gcn, bcnt, h128);
  k_split<<<NSPLIT, 256, 0, stream>>>(src, dst, bcnt, staging);
  k_place<<<B1, 256, 0, stream>>>(staging, bcnt, csr_src, rs, dinv);

  // fused front-end (gather+project+combine) -> hs
  k_front<<<nb16, 256, 0, stream>>>(x, poi_emb, cat_emb, W_in, wf_in, dinv, hs);

  k_agg<0><<<nb4, 256, 0, stream>>>(hs, rs, csr_src, dinv, b_in, feat, nullptr,
                                    nullptr);
  for (int l = 0; l < 5; l++) {
    k_projg<<<nb16, 256, 0, stream>>>(feat, wf_gcn + (size_t)l * 4096, hs, dinv);
    if (l < 4)
      k_agg<1><<<nb4, 256, 0, stream>>>(hs, rs, csr_src, dinv,
                                        gcn_bs + (size_t)l * 64, feat, nullptr,
                                        nullptr);
    else
      k_agg<2><<<nb4, 256, 0, stream>>>(hs, rs, csr_src, dinv,
                                        gcn_bs + (size_t)l * 64, nullptr, W_out,
                                        hs1);
  }

  k_out_agg<<<nb4, 256, 0, stream>>>(hs1, rs, csr_src, dinv, b_out, g);
  k_fc1<<<(N_NODES + 31) / 32, 128, 0, stream>>>(g, fc1_W, h128);
  k_fc2<<<(POI_LEN + 255) / 256, 256, 0, stream>>>(h128, fc1_b, fc2_W, fc2_b, out);
}

// Round 2
// 407.480 us; speedup vs baseline: 1.1430x; 1.0648x over previous
//
#include <hip/hip_runtime.h>
#include <hip/hip_bf16.h>

#define N_NODES 38332
#define POI_LEN 38333
#define CAT_LEN 400
#define POI_DIM 300
#define CAT_DIM 100
#define N_EDGES (N_NODES * 32)
#define NEG_SLOPE 0.01f
#define B1 ((N_NODES + 127) / 128)        // 300 dst-buckets (128 dsts each)
#define SPLIT_CHUNK 2048
#define NSPLIT ((N_EDGES + SPLIT_CHUNK - 1) / SPLIT_CHUNK)  // 599
#define PLACE_CAP 8192
#define BCAP 8192                          // per-bucket staging/csr capacity

typedef __attribute__((ext_vector_type(8))) short short8;
typedef __attribute__((ext_vector_type(4))) float f32x4;

__device__ __forceinline__ unsigned short f2bf(float f) {
  unsigned u = __float_as_uint(f);
  u += 0x7fff + ((u >> 16) & 1);  // RNE
  return (unsigned short)(u >> 16);
}
__device__ __forceinline__ float bflo(unsigned u) {
  return __uint_as_float(u << 16);
}
__device__ __forceinline__ float bfhi(unsigned u) {
  return __uint_as_float(u & 0xffff0000u);
}

// ---------------- prep: zero counters + all W swizzles in ONE kernel -------
// wf layout (B-frag order): idx = (((ks*4+q)*64 + n)*8 + j), k = ks*32+q*8+j

#define WFIN_ELEMS (13 * 2048)   // K_pad=416 -> 26624
#define WFGCN_ELEMS (5 * 4096)

__global__ __launch_bounds__(256) void k_prep(const float* __restrict__ W_in,
                                              const float* __restrict__ gcn_Ws,
                                              unsigned short* __restrict__ wf_in,
                                              unsigned short* __restrict__ wf_gcn,
                                              int* __restrict__ bcnt,
                                              float* __restrict__ h128) {
  int idx = blockIdx.x * 256 + threadIdx.x;
  if (idx < B1) bcnt[idx] = 0;
  if (idx < 128) h128[idx] = 0.f;
  if (idx < WFIN_ELEMS) {
    int j = idx & 7, n = (idx >> 3) & 63, q = (idx >> 9) & 3, ks = idx >> 11;
    int k = ks * 32 + q * 8 + j;
    wf_in[idx] = f2bf((k < 400) ? W_in[k * 64 + n] : 0.f);
  } else if (idx < WFIN_ELEMS + WFGCN_ELEMS) {
    int t = idx - WFIN_ELEMS;
    int l = t >> 12, i = t & 4095;
    int j = i & 7, n = (i >> 3) & 63, q = (i >> 9) & 3, ks = i >> 11;
    int k = ks * 32 + q * 8 + j;
    wf_gcn[t] = f2bf(gcn_Ws[(size_t)l * 4096 + k * 64 + n]);
  }
}

// ---------------- CSR build (count-free, two-level, packed staging) --------
// staging entry packs (src << 7) | (dst & 127): src < 38332 < 2^16 fits.

__global__ __launch_bounds__(256) void k_split(const int* __restrict__ src,
                                               const int* __restrict__ dst,
                                               int* __restrict__ bcnt,
                                               int* __restrict__ staging) {
  __shared__ int hist[B1];
  __shared__ int lbase[B1];
  __shared__ int lcur[B1];
  int tid = threadIdx.x;
  int base = blockIdx.x * SPLIT_CHUNK;
  int n = N_EDGES - base;
  if (n > SPLIT_CHUNK) n = SPLIT_CHUNK;
  for (int b = tid; b < B1; b += 256) {
    hist[b] = 0;
    lcur[b] = 0;
  }
  __syncthreads();
  for (int i = tid; i < n; i += 256) atomicAdd(&hist[dst[base + i] >> 7], 1);
  __syncthreads();
  for (int b = tid; b < B1; b += 256) {
    int c = hist[b];
    lbase[b] = c ? atomicAdd(&bcnt[b], c) : 0;
  }
  __syncthreads();
  for (int i = tid; i < n; i += 256) {
    int d = dst[base + i];
    int s = src[base + i];
    int b = d >> 7;
    int off = atomicAdd(&lcur[b], 1);
    staging[(size_t)b * BCAP + lbase[b] + off] = (s << 7) | (d & 127);
  }
}

// per bucket: local histogram + scan -> rs(start,cnt)/dinv, exact placement
// in LDS, coalesced copy-out into the bucket's fixed csr region.
__global__ __launch_bounds__(256) void k_place(const int* __restrict__ staging,
                                               const int* __restrict__ bcnt,
                                               int* __restrict__ csr_src,
                                               int2* __restrict__ rs,
                                               float* __restrict__ dinv) {
  __shared__ int lc[128];
  __shared__ int ls[256];
  __shared__ int cur[128];
  __shared__ int buf[PLACE_CAP];
  int b = blockIdx.x;
  int tid = threadIdx.x;
  int d0 = b * 128;
  int nd = N_NODES - d0;
  if (nd > 128) nd = 128;
  int cnt_b = bcnt[b];
  const int* st = staging + (size_t)b * BCAP;
  if (tid < 128) lc[tid] = 0;
  __syncthreads();
  for (int i = tid; i < cnt_b; i += 256) atomicAdd(&lc[st[i] & 127], 1);
  __syncthreads();
  int v = (tid < 128) ? lc[tid] : 0;
  ls[tid] = v;
  __syncthreads();
  for (int off = 1; off < 128; off <<= 1) {
    int t = (tid >= off) ? ls[tid - off] : 0;
    __syncthreads();
    ls[tid] += t;
    __syncthreads();
  }
  if (tid < 128) {
    int excl = ls[tid] - v;
    cur[tid] = excl;
    if (tid < nd) {
      rs[d0 + tid] = make_int2(b * BCAP + excl, v);
      dinv[d0 + tid] = 1.0f / sqrtf((float)(v + 1));  // deg incl self loop
    }
  }
  __syncthreads();
  for (int i = tid; i < cnt_b; i += 256) {
    int p = st[i];
    int pos = atomicAdd(&cur[p & 127], 1);
    buf[pos] = p >> 7;
  }
  __syncthreads();
  int base = b * BCAP;
  for (int i = tid; i < cnt_b; i += 256) csr_src[base + i] = buf[i];
}

// ---------------- fused front-end: gather poi/cat rows + MFMA GEMM -> hs ---

__global__ __launch_bounds__(256) void k_front(
    const float* __restrict__ x, const float* __restrict__ poi_emb,
    const float* __restrict__ cat_emb, const float* __restrict__ W_in,
    const unsigned short* __restrict__ wf_in, const float* __restrict__ dinv,
    unsigned short* __restrict__ hs) {
  constexpr int KP = 416, RS = 424, NK4 = 104;
  __shared__ unsigned short sA[16 * RS];
  __shared__ float sC[16 * 68];
  __shared__ int sPid[16], sCid[16];
  __shared__ float sX[16][3];
  int tid = threadIdx.x;
  int row0 = blockIdx.x * 16;
  if (tid < 16) {
    int row = row0 + tid;
    if (row < N_NODES) {
      sPid[tid] = (int)x[row * 5 + 0];
      sCid[tid] = (int)x[row * 5 + 1];
      sX[tid][0] = x[row * 5 + 2];
      sX[tid][1] = x[row * 5 + 3];
      sX[tid][2] = x[row * 5 + 4];
    } else {
      sPid[tid] = 0; sCid[tid] = 0;
      sX[tid][0] = sX[tid][1] = sX[tid][2] = 0.f;
    }
  }
  __syncthreads();
  for (int idx = tid; idx < 16 * NK4; idx += 256) {
    int r = idx / NK4;
    int k = (idx - r * NK4) * 4;
    ushort4 o = {0, 0, 0, 0};
    if (k < 400 && row0 + r < N_NODES) {
      float4 f;
      if (k < 300) f = *(const float4*)(poi_emb + (size_t)sPid[r] * 300 + k);
      else         f = *(const float4*)(cat_emb + (size_t)sCid[r] * 100 + (k - 300));
      o.x = f2bf(f.x); o.y = f2bf(f.y); o.z = f2bf(f.z); o.w = f2bf(f.w);
    }
    *(ushort4*)&sA[r * RS + k] = o;
  }
  __syncthreads();
  int lane = tid & 63, wv = tid >> 6;
  int c = lane & 15, q = lane >> 4, n0 = wv * 16;
  f32x4 acc = {0.f, 0.f, 0.f, 0.f};
  const unsigned short* arow = &sA[c * RS];
#pragma unroll
  for (int ks = 0; ks < KP / 32; ks++) {
    short8 af = *(const short8*)(arow + ks * 32 + q * 8);
    short8 bf = *(const short8*)(wf_in + ((size_t)((ks * 4 + q) * 64 + n0 + c)) * 8);
    acc = __builtin_amdgcn_mfma_f32_16x16x32_bf16(af, bf, acc, 0, 0, 0);
  }
#pragma unroll
  for (int r = 0; r < 4; r++) sC[(q * 4 + r) * 68 + n0 + c] = acc[r];
  __syncthreads();
  for (int idx = tid; idx < 16 * 64; idx += 256) {
    int r = idx >> 6, col = idx & 63;
    int row = row0 + r;
    if (row < N_NODES) {
      float v = sC[r * 68 + col] + sX[r][0] * W_in[400 * 64 + col] +
                sX[r][1] * W_in[401 * 64 + col] + sX[r][2] * W_in[402 * 64 + col];
      hs[(size_t)row * 64 + col] = f2bf(v * dinv[row]);
    }
  }
}

// ------- aggregation + FUSED projection: one kernel per GCN layer ---------
// wave = 1 dst node (4 nodes/block). Aggregate neighbors (4 gathers in
// flight), shuffle-reduce, epilogue computes t -> leaky -> o.
// MODE 0: o = leaky(t);        then hs_next = bf16((o @ Wf) * dinv)  (MFMA)
// MODE 1: o = leaky(t) + t;    then hs_next = bf16((o @ Wf) * dinv)  (MFMA)
// MODE 2: o = leaky(t) + t;    hs1 = (o . W_out) * dinv   (no feat/hs write)
// The MFMA uses a 16-row A-tile with only rows 0..3 valid (rows 4..15
// zeroed) — MFMA time is negligible net-wide, tile waste is free, and this
// deletes the separate k_projg kernel + the feat global round-trip.

template <int MODE>
__global__ __launch_bounds__(256) void k_agg(const unsigned short* __restrict__ hs,
                                             const int2* __restrict__ rs,
                                             const int* __restrict__ csr_src,
                                             const float* __restrict__ dinv,
                                             const float* __restrict__ bias,
                                             const unsigned short* __restrict__ Wf,
                                             unsigned short* __restrict__ hs_next,
                                             const float* __restrict__ W_out,
                                             float* __restrict__ hs1) {
  __shared__ unsigned short sA[16 * 72];  // A-tile, rows 0..3 = this block
  __shared__ float sC[4 * 68];
  int tid = threadIdx.x;
  int lane = tid & 63;
  int wv = tid >> 6;
  int node = blockIdx.x * 4 + wv;
  int eslot = lane >> 3;  // 0..7
  int ch8 = lane & 7;     // 8-channel group (16B) within 64-ch row
  if (MODE != 2) {
    // zero A-tile rows 4..15 (rows 0..3 cols 0..63 fully written below)
    for (int i = tid; i < 216; i += 256)
      *(ushort4*)&sA[288 + i * 4] = (ushort4){0, 0, 0, 0};
  }
  int2 rr = rs[node];
  int r0 = rr.x, r1 = rr.x + rr.y;
  float4 a0 = {0.f, 0.f, 0.f, 0.f}, a1 = a0;
#define ACC8(v)                                                              \
  do {                                                                       \
    a0.x += bflo((v).x); a0.y += bfhi((v).x);                                \
    a0.z += bflo((v).y); a0.w += bfhi((v).y);                                \
    a1.x += bflo((v).z); a1.y += bfhi((v).z);                                \
    a1.z += bflo((v).w); a1.w += bfhi((v).w);                                \
  } while (0)
  int e = r0 + eslot;
  for (; e + 24 < r1; e += 32) {
    int s0 = csr_src[e];
    int s1 = csr_src[e + 8];
    int s2 = csr_src[e + 16];
    int s3 = csr_src[e + 24];
    uint4 v0 = *(const uint4*)(hs + (size_t)s0 * 64 + ch8 * 8);
    uint4 v1 = *(const uint4*)(hs + (size_t)s1 * 64 + ch8 * 8);
    uint4 v2 = *(const uint4*)(hs + (size_t)s2 * 64 + ch8 * 8);
    uint4 v3 = *(const uint4*)(hs + (size_t)s3 * 64 + ch8 * 8);
    ACC8(v0); ACC8(v1); ACC8(v2); ACC8(v3);
  }
  if (e + 8 < r1) {
    int s0 = csr_src[e];
    int s1 = csr_src[e + 8];
    uint4 v0 = *(const uint4*)(hs + (size_t)s0 * 64 + ch8 * 8);
    uint4 v1 = *(const uint4*)(hs + (size_t)s1 * 64 + ch8 * 8);
    ACC8(v0); ACC8(v1);
    e += 16;
  }
  if (e < r1) {
    int s = csr_src[e];
    uint4 v = *(const uint4*)(hs + (size_t)s * 64 + ch8 * 8);
    ACC8(v);
  }
#undef ACC8
#pragma unroll
  for (int off = 8; off <= 32; off <<= 1) {
    a0.x += __shfl_xor(a0.x, off, 64);
    a0.y += __shfl_xor(a0.y, off, 64);
    a0.z += __shfl_xor(a0.z, off, 64);
    a0.w += __shfl_xor(a0.w, off, 64);
    a1.x += __shfl_xor(a1.x, off, 64);
    a1.y += __shfl_xor(a1.y, off, 64);
    a1.z += __shfl_xor(a1.z, off, 64);
    a1.w += __shfl_xor(a1.w, off, 64);
  }
  float dn = dinv[node];
  if (lane < 8) {
    uint4 sv = *(const uint4*)(hs + (size_t)node * 64 + ch8 * 8);
    float4 bb0 = *(const float4*)(bias + ch8 * 8);
    float4 bb1 = *(const float4*)(bias + ch8 * 8 + 4);
    float4 t0, t1;
    t0.x = dn * (a0.x + bflo(sv.x)) + bb0.x;
    t0.y = dn * (a0.y + bfhi(sv.x)) + bb0.y;
    t0.z = dn * (a0.z + bflo(sv.y)) + bb0.z;
    t0.w = dn * (a0.w + bfhi(sv.y)) + bb0.w;
    t1.x = dn * (a1.x + bflo(sv.z)) + bb1.x;
    t1.y = dn * (a1.y + bfhi(sv.z)) + bb1.y;
    t1.z = dn * (a1.z + bflo(sv.w)) + bb1.z;
    t1.w = dn * (a1.w + bfhi(sv.w)) + bb1.w;
    float4 l0, l1, o0, o1;
    l0.x = (t0.x >= 0.f) ? t0.x : NEG_SLOPE * t0.x;
    l0.y = (t0.y >= 0.f) ? t0.y : NEG_SLOPE * t0.y;
    l0.z = (t0.z >= 0.f) ? t0.z : NEG_SLOPE * t0.z;
    l0.w = (t0.w >= 0.f) ? t0.w : NEG_SLOPE * t0.w;
    l1.x = (t1.x >= 0.f) ? t1.x : NEG_SLOPE * t1.x;
    l1.y = (t1.y >= 0.f) ? t1.y : NEG_SLOPE * t1.y;
    l1.z = (t1.z >= 0.f) ? t1.z : NEG_SLOPE * t1.z;
    l1.w = (t1.w >= 0.f) ? t1.w : NEG_SLOPE * t1.w;
    if (MODE == 0) {
      o0 = l0; o1 = l1;
    } else {
      o0.x = l0.x + t0.x; o0.y = l0.y + t0.y; o0.z = l0.z + t0.z; o0.w = l0.w + t0.w;
      o1.x = l1.x + t1.x; o1.y = l1.y + t1.y; o1.z = l1.z + t1.z; o1.w = l1.w + t1.w;
    }
    if (MODE == 2) {
      float4 w0 = *(const float4*)(W_out + ch8 * 8);
      float4 w1 = *(const float4*)(W_out + ch8 * 8 + 4);
      float p = o0.x * w0.x + o0.y * w0.y + o0.z * w0.z + o0.w * w0.w +
                o1.x * w1.x + o1.y * w1.y + o1.z * w1.z + o1.w * w1.w;
      p += __shfl_xor(p, 1, 64);
      p += __shfl_xor(p, 2, 64);
      p += __shfl_xor(p, 4, 64);
      if (lane == 0) hs1[node] = p * dn;
    } else {
      uint4 pk;
      pk.x = (unsigned)f2bf(o0.x) | ((unsigned)f2bf(o0.y) << 16);
      pk.y = (unsigned)f2bf(o0.z) | ((unsigned)f2bf(o0.w) << 16);
      pk.z = (unsigned)f2bf(o1.x) | ((unsigned)f2bf(o1.y) << 16);
      pk.w = (unsigned)f2bf(o1.z) | ((unsigned)f2bf(o1.w) << 16);
      *(uint4*)&sA[wv * 72 + ch8 * 8] = pk;  // bf16 feat row -> A-tile
    }
  }
  if (MODE != 2) {
    __syncthreads();
    // 16x16x32 MFMA over K=64 (2 steps): hs_next = bf16((A @ Wf) * dinv)
    int c = lane & 15, q = lane >> 4, n0 = wv * 16;
    f32x4 acc = {0.f, 0.f, 0.f, 0.f};
    const unsigned short* arow = &sA[c * 72];
#pragma unroll
    for (int ks = 0; ks < 2; ks++) {
      short8 af = *(const short8*)(arow + ks * 32 + q * 8);
      short8 bf = *(const short8*)(Wf + ((size_t)((ks * 4 + q) * 64 + n0 + c)) * 8);
      acc = __builtin_amdgcn_mfma_f32_16x16x32_bf16(af, bf, acc, 0, 0, 0);
    }
    if (q == 0) {  // rows 0..3 only
#pragma unroll
      for (int r = 0; r < 4; r++) sC[r * 68 + n0 + c] = acc[r];
    }
    __syncthreads();
    if (tid < 128) {
      int r = tid >> 5, c2 = (tid & 31) * 2;
      int row = blockIdx.x * 4 + r;
      float dr = dinv[row];
      unsigned lo = f2bf(sC[r * 68 + c2] * dr);
      unsigned hi = f2bf(sC[r * 68 + c2 + 1] * dr);
      *(unsigned*)(hs_next + (size_t)row * 64 + c2) = lo | (hi << 16);
    }
  }
}

// ---------------- output aggregation (64 -> 1 head, post-xform) ------------

__global__ __launch_bounds__(256) void k_out_agg(const float* __restrict__ hs1,
                                                 const int2* __restrict__ rs,
                                                 const int* __restrict__ csr_src,
                                                 const float* __restrict__ dinv,
                                                 const float* __restrict__ b_out,
                                                 float* __restrict__ g) {
  int lane = threadIdx.x & 63;
  int w = threadIdx.x >> 6;
  int node = blockIdx.x * 4 + w;
  int2 rr = rs[node];
  int r0 = rr.x, r1 = rr.x + rr.y;
  float acc = 0.f;
  for (int e = r0 + lane; e < r1; e += 64) acc += hs1[csr_src[e]];
#pragma unroll
  for (int off = 32; off; off >>= 1) acc += __shfl_xor(acc, off, 64);
  if (lane == 0) {
    float t = dinv[node] * (acc + hs1[node]) + b_out[0];
    g[node] = (t >= 0.f) ? t : NEG_SLOPE * t;
  }
}

// ---------------- FC head ----------------

__global__ __launch_bounds__(128) void k_fc1(const float* __restrict__ g,
                                             const float* __restrict__ fc1_W,
                                             float* __restrict__ h128) {
  int j = threadIdx.x;  // 0..127
  int base = blockIdx.x * 32;
  int end = base + 32;
  if (end > N_NODES) end = N_NODES;
  float acc = 0.f;
  int i = base;
  for (; i + 4 <= end; i += 4) {
    acc += g[i + 0] * fc1_W[(size_t)(i + 0) * 128 + j];
    acc += g[i + 1] * fc1_W[(size_t)(i + 1) * 128 + j];
    acc += g[i + 2] * fc1_W[(size_t)(i + 2) * 128 + j];
    acc += g[i + 3] * fc1_W[(size_t)(i + 3) * 128 + j];
  }
  for (; i < end; i++) acc += g[i] * fc1_W[(size_t)i * 128 + j];
  atomicAdd(&h128[j], acc);
}

__global__ __launch_bounds__(256) void k_fc2(const float* __restrict__ h128raw,
                                             const float* __restrict__ fc1_b,
                                             const float* __restrict__ fc2_W,
                                             const float* __restrict__ fc2_b,
                                             float* __restrict__ out) {
  __shared__ float sh[128];
  int tid = threadIdx.x;
  if (tid < 128) {
    float v = h128raw[tid] + fc1_b[tid];
    sh[tid] = (v > 0.f) ? v : 0.f;
  }
  __syncthreads();
  int p = blockIdx.x * 256 + tid;
  if (p < POI_LEN) {
    float acc = fc2_b[p];
#pragma unroll 8
    for (int j = 0; j < 128; j++) acc += sh[j] * fc2_W[(size_t)j * POI_LEN + p];
    out[p] = (acc > 0.f) ? acc : 0.f;
  }
}

// ---------------- launch ----------------

extern "C" void kernel_launch(void* const* d_in, const int* in_sizes, int n_in,
                              void* d_out, int out_size, void* d_ws, size_t ws_size,
                              hipStream_t stream) {
  const float* x       = (const float*)d_in[0];
  const int*   ei      = (const int*)d_in[1];
  const float* poi_emb = (const float*)d_in[2];
  const float* cat_emb = (const float*)d_in[3];
  const float* W_in    = (const float*)d_in[4];
  const float* b_in    = (const float*)d_in[5];
  const float* gcn_Ws  = (const float*)d_in[6];
  const float* gcn_bs  = (const float*)d_in[7];
  const float* W_out   = (const float*)d_in[8];
  const float* b_out   = (const float*)d_in[9];
  const float* fc1_W   = (const float*)d_in[10];
  const float* fc1_b   = (const float*)d_in[11];
  const float* fc2_W   = (const float*)d_in[12];
  const float* fc2_b   = (const float*)d_in[13];
  const int* src = ei;
  const int* dst = ei + N_EDGES;

  char* p = (char*)d_ws;
  auto take = [&](size_t bytes) {
    char* r = p;
    p += (bytes + 255) & ~(size_t)255;
    return r;
  };
  int2*  rs        = (int2*)take((size_t)N_NODES * 8);
  float* dinv      = (float*)take((size_t)N_NODES * 4);
  int*   bcnt      = (int*)take((size_t)B1 * 4);
  int*   csr_src   = (int*)take((size_t)B1 * BCAP * 4);
  unsigned short* hsA = (unsigned short*)take((size_t)N_NODES * 64 * 2);
  unsigned short* hsB = (unsigned short*)take((size_t)N_NODES * 64 * 2);
  float* hs1       = (float*)take((size_t)N_NODES * 4);
  float* g         = (float*)take((size_t)N_NODES * 4);
  float* h128      = (float*)take(128 * 4);
  unsigned short* wf_in  = (unsigned short*)take((size_t)WFIN_ELEMS * 2);
  unsigned short* wf_gcn = (unsigned short*)take((size_t)WFGCN_ELEMS * 2);
  // staging (9.83 MB int) aliases hsA+hsB+hs1 (9.97 MB) — all dead until
  // after k_place finishes reading staging.
  int* staging = (int*)hsA;
  float* out = (float*)d_out;

  const int nb4 = N_NODES / 4;           // 9583
  const int nb16 = (N_NODES + 15) / 16;  // 2396

  k_prep<<<(WFIN_ELEMS + WFGCN_ELEMS + 255) / 256, 256, 0, stream>>>(
      W_in, gcn_Ws, wf_in, wf_gcn, bcnt, h128);
  k_split<<<NSPLIT, 256, 0, stream>>>(src, dst, bcnt, staging);
  k_place<<<B1, 256, 0, stream>>>(staging, bcnt, csr_src, rs, dinv);

  // fused front-end (gather+project+combine) -> hsA
  k_front<<<nb16, 256, 0, stream>>>(x, poi_emb, cat_emb, W_in, wf_in, dinv, hsA);

  // 6 fused agg+proj layers, ping-pong hsA/hsB
  k_agg<0><<<nb4, 256, 0, stream>>>(hsA, rs, csr_src, dinv, b_in,
                                    wf_gcn + 0 * 4096, hsB, nullptr, nullptr);
  k_agg<1><<<nb4, 256, 0, stream>>>(hsB, rs, csr_src, dinv, gcn_bs + 0 * 64,
                                    wf_gcn + 1 * 4096, hsA, nullptr, nullptr);
  k_agg<1><<<nb4, 256, 0, stream>>>(hsA, rs, csr_src, dinv, gcn_bs + 1 * 64,
                                    wf_gcn + 2 * 4096, hsB, nullptr, nullptr);
  k_agg<1><<<nb4, 256, 0, stream>>>(hsB, rs, csr_src, dinv, gcn_bs + 2 * 64,
                                    wf_gcn + 3 * 4096, hsA, nullptr, nullptr);
  k_agg<1><<<nb4, 256, 0, stream>>>(hsA, rs, csr_src, dinv, gcn_bs + 3 * 64,
                                    wf_gcn + 4 * 4096, hsB, nullptr, nullptr);
  k_agg<2><<<nb4, 256, 0, stream>>>(hsB, rs, csr_src, dinv, gcn_bs + 4 * 64,
                                    nullptr, nullptr, W_out, hs1);

  k_out_agg<<<nb4, 256, 0, stream>>>(hs1, rs, csr_src, dinv, b_out, g);
  k_fc1<<<(N_NODES + 31) / 32, 128, 0, stream>>>(g, fc1_W, h128);
  k_fc2<<<(POI_LEN + 255) / 256, 256, 0, stream>>>(h128, fc1_b, fc2_W, fc2_b, out);
}